// Round 2
// baseline (359.676 us; speedup 1.0000x reference)
//
#include <hip/hip_runtime.h>

// Problem constants (fixed by setup_inputs)
#define B_      4
#define C_UNI   64
#define H_      512
#define W_      512
#define HW      (H_ * W_)        // 262144 = 2^18
#define HW_LOG2 18
#define N_PIX   (B_ * HW)        // 1,048,576 pixels
#define NBLOCKS 2048             // N_PIX / 2 px-per-thread / 256 threads
#define IGNORE_INDEX 255

typedef float f32x2 __attribute__((ext_vector_type(2)));

// R6 single-variable experiment: R5 == R4 to 0.01% despite totally different
// occupancy/width/accumulator structure -> occupancy & MLP are NOT the
// bottleneck. The one shared factor on the 272 MB input stream is the
// nontemporal flag. This version = R5 with nt REMOVED (plain cached loads),
// everything else identical. If nt was forcing a slow LLC-bypass path,
// main drops to the ~85 us read+writeback floor; if unchanged, nt is
// exonerated and next step is an access-pattern transpose.

__global__ __launch_bounds__(256, 8) void uni_ce_main(
    const float* __restrict__ inp,      // [B, C_UNI, H, W]
    const int*   __restrict__ targets,  // [B, H, W]
    const int*   __restrict__ gids,     // [C_UNI]
    float2*      __restrict__ partial)  // [NBLOCKS] {loss_sum, valid_cnt}
{
    __shared__ int s_gid[C_UNI];
    const int tid = threadIdx.x;
    if (tid < C_UNI) s_gid[tid] = gids[tid];
    __syncthreads();

    const int g    = blockIdx.x * blockDim.x + tid;   // [0, N_PIX/2)
    const int base = g << 1;                          // first pixel index
    const int b    = base >> HW_LOG2;                 // block-uniform (512 px/block)
    const int pix  = base & (HW - 1);

    const int2 t2 = *(const int2*)(targets + base);

    const float* p = inp + (((size_t)(b * C_UNI)) << HW_LOG2) + pix;

    float den0 = 0.f, den1 = 0.f, num0 = 0.f, num1 = 0.f;

    #pragma unroll 8
    for (int c = 0; c < C_UNI; ++c) {
        const f32x2 x = *(const f32x2*)(p + ((size_t)c << HW_LOG2));
        const float e0 = __expf(x.x);
        const float e1 = __expf(x.y);
        den0 += e0;
        den1 += e1;
        const int gc = s_gid[c];                      // wave-uniform broadcast
        if (gc == t2.x) num0 += e0;
        if (gc == t2.y) num1 += e1;
    }

    float loss = 0.f, cnt = 0.f;
    if (t2.x != IGNORE_INDEX) { loss += __logf(den0) - __logf(num0); cnt += 1.f; }
    if (t2.y != IGNORE_INDEX) { loss += __logf(den1) - __logf(num1); cnt += 1.f; }

    // 64-lane wave reduction
    #pragma unroll
    for (int off = 32; off > 0; off >>= 1) {
        loss += __shfl_down(loss, off);
        cnt  += __shfl_down(cnt,  off);
    }

    __shared__ float s_loss[4];
    __shared__ float s_cnt[4];
    const int wave = tid >> 6;
    const int lane = tid & 63;
    if (lane == 0) { s_loss[wave] = loss; s_cnt[wave] = cnt; }
    __syncthreads();
    if (tid == 0) {
        float2 pr;
        pr.x = s_loss[0] + s_loss[1] + s_loss[2] + s_loss[3];
        pr.y = s_cnt[0]  + s_cnt[1]  + s_cnt[2]  + s_cnt[3];
        partial[blockIdx.x] = pr;
    }
}

// Reduce 2048 float2 partials -> scalar loss. One block of 256 threads;
// each thread reads 8 partials via four float4 loads (tid*64B, aligned).
__global__ __launch_bounds__(256) void uni_ce_final(
    const float2* __restrict__ partial,
    float*        __restrict__ out)
{
    const int tid = threadIdx.x;
    const float4 q0 = *(const float4*)(partial + tid * 8);
    const float4 q1 = *(const float4*)(partial + tid * 8 + 2);
    const float4 q2 = *(const float4*)(partial + tid * 8 + 4);
    const float4 q3 = *(const float4*)(partial + tid * 8 + 6);
    float loss = q0.x + q0.z + q1.x + q1.z + q2.x + q2.z + q3.x + q3.z;
    float cnt  = q0.y + q0.w + q1.y + q1.w + q2.y + q2.w + q3.y + q3.w;

    #pragma unroll
    for (int off = 32; off > 0; off >>= 1) {
        loss += __shfl_down(loss, off);
        cnt  += __shfl_down(cnt,  off);
    }

    __shared__ float s_loss[4];
    __shared__ float s_cnt[4];
    const int wave = tid >> 6;
    const int lane = tid & 63;
    if (lane == 0) { s_loss[wave] = loss; s_cnt[wave] = cnt; }
    __syncthreads();
    if (tid == 0) {
        const float L = s_loss[0] + s_loss[1] + s_loss[2] + s_loss[3];
        const float C = s_cnt[0]  + s_cnt[1]  + s_cnt[2]  + s_cnt[3];
        out[0] = L / fmaxf(C, 1.0f);
    }
}

extern "C" void kernel_launch(void* const* d_in, const int* in_sizes, int n_in,
                              void* d_out, int out_size, void* d_ws, size_t ws_size,
                              hipStream_t stream) {
    const float* inp = (const float*)d_in[0];
    const int*   tgt = (const int*)d_in[1];
    const int*   gid = (const int*)d_in[2];
    float* out = (float*)d_out;
    float2* partial = (float2*)d_ws;   // 2048 float2 = 16 KiB, written before read

    const int threads = 256;
    uni_ce_main<<<NBLOCKS, threads, 0, stream>>>(inp, tgt, gid, partial);
    uni_ce_final<<<1, threads, 0, stream>>>(partial, out);
}

// Round 3
// 338.360 us; speedup vs baseline: 1.0630x; 1.0630x over previous
//
#include <hip/hip_runtime.h>

// Problem constants (fixed by setup_inputs)
#define B_      4
#define C_UNI   64
#define H_      512
#define W_      512
#define HW      (H_ * W_)        // 262144 = 2^18
#define HW_LOG2 18
#define N_PIX   (B_ * HW)        // 1,048,576 pixels
#define IGNORE_INDEX 255

#define TILE_PX 4096             // pixels per block -> 16 KiB contiguous per channel visit
#define NBLOCKS (N_PIX / TILE_PX)   // 256 blocks = 1 per CU
#define THREADS 512              // 8 waves; 8 px per thread

typedef float f32x4 __attribute__((ext_vector_type(4)));

#define NT_LOAD(ptr) __builtin_nontemporal_load((const f32x4*)(ptr))

// R7: DRAM-row-locality restructure.
// History: R4(335.4) == R5(335.5) despite opposite occupancy/width/accum
// structure -> SIMT-side knobs falsified. R6 (nt removed) = 359.7 (+24us,
// the LLC writeback shadow) -> nt stays, and main is confirmed a real
// ~155-160us dispatch at ~1.7 TB/s (27% of achievable).
// Shared factor in all slow versions: 64 channel streams at exactly 1 MiB
// stride with only 2-4 KiB contiguous per visit. 1 MiB stride preserves all
// HBM channel/bank interleave bits -> per pixel-chunk, 64 visits hit the
// same bank on 64 different rows -> tRC-limited row thrash.
// This version: block owns a 4096-px tile, per-pixel den/num in REGISTERS
// (8 px/thread), streams each channel as a 16 KiB contiguous run (8x longer),
// 1-deep prefetch of the next channel. 256 blocks (1/CU), 8 waves each.

__global__ __launch_bounds__(THREADS) void uni_ce_main(
    const float* __restrict__ inp,      // [B, C_UNI, H, W]
    const int*   __restrict__ targets,  // [B, H, W]
    const int*   __restrict__ gids,     // [C_UNI]
    float2*      __restrict__ partial)  // [NBLOCKS] {loss_sum, valid_cnt}
{
    __shared__ int s_gid[C_UNI];
    const int tid = threadIdx.x;
    if (tid < C_UNI) s_gid[tid] = gids[tid];
    __syncthreads();

    const int tilepx = blockIdx.x * TILE_PX;          // global flat pixel index
    const int b      = tilepx >> HW_LOG2;             // tile never crosses b
    const int pix    = tilepx & (HW - 1);

    const float* p = inp + (((size_t)(b * C_UNI)) << HW_LOG2) + pix;

    // two f32x4 groups per thread: elems [e0..e0+3] and [e1..e1+3] of the tile
    const int e0 = tid * 4;                           // step 0: elems 0..2047
    const int e1 = 2048 + tid * 4;                    // step 1: elems 2048..4095

    const int4 tg0 = *(const int4*)(targets + tilepx + e0);
    const int4 tg1 = *(const int4*)(targets + tilepx + e1);

    float den0x = 0.f, den0y = 0.f, den0z = 0.f, den0w = 0.f;
    float den1x = 0.f, den1y = 0.f, den1z = 0.f, den1w = 0.f;
    float num0x = 0.f, num0y = 0.f, num0z = 0.f, num0w = 0.f;
    float num1x = 0.f, num1y = 0.f, num1z = 0.f, num1w = 0.f;

    f32x4 cur0 = NT_LOAD(p + e0);
    f32x4 cur1 = NT_LOAD(p + e1);

    #pragma unroll 1
    for (int c = 0; c < C_UNI - 1; ++c) {
        // prefetch next channel (16 KiB contiguous per block) before compute
        const float* pn = p + (((size_t)(c + 1)) << HW_LOG2);
        const f32x4 nxt0 = NT_LOAD(pn + e0);
        const f32x4 nxt1 = NT_LOAD(pn + e1);

        const int gc = s_gid[c];

        const float a0 = __expf(cur0.x), a1 = __expf(cur0.y),
                    a2 = __expf(cur0.z), a3 = __expf(cur0.w);
        const float b0 = __expf(cur1.x), b1 = __expf(cur1.y),
                    b2 = __expf(cur1.z), b3 = __expf(cur1.w);
        den0x += a0; den0y += a1; den0z += a2; den0w += a3;
        den1x += b0; den1y += b1; den1z += b2; den1w += b3;
        if (gc == tg0.x) num0x += a0;
        if (gc == tg0.y) num0y += a1;
        if (gc == tg0.z) num0z += a2;
        if (gc == tg0.w) num0w += a3;
        if (gc == tg1.x) num1x += b0;
        if (gc == tg1.y) num1y += b1;
        if (gc == tg1.z) num1z += b2;
        if (gc == tg1.w) num1w += b3;

        cur0 = nxt0;
        cur1 = nxt1;
    }
    {   // peeled last channel (no prefetch)
        const int gc = s_gid[C_UNI - 1];
        const float a0 = __expf(cur0.x), a1 = __expf(cur0.y),
                    a2 = __expf(cur0.z), a3 = __expf(cur0.w);
        const float b0 = __expf(cur1.x), b1 = __expf(cur1.y),
                    b2 = __expf(cur1.z), b3 = __expf(cur1.w);
        den0x += a0; den0y += a1; den0z += a2; den0w += a3;
        den1x += b0; den1y += b1; den1z += b2; den1w += b3;
        if (gc == tg0.x) num0x += a0;
        if (gc == tg0.y) num0y += a1;
        if (gc == tg0.z) num0z += a2;
        if (gc == tg0.w) num0w += a3;
        if (gc == tg1.x) num1x += b0;
        if (gc == tg1.y) num1y += b1;
        if (gc == tg1.z) num1z += b2;
        if (gc == tg1.w) num1w += b3;
    }

    float loss = 0.f, cnt = 0.f;
    if (tg0.x != IGNORE_INDEX) { loss += __logf(den0x) - __logf(num0x); cnt += 1.f; }
    if (tg0.y != IGNORE_INDEX) { loss += __logf(den0y) - __logf(num0y); cnt += 1.f; }
    if (tg0.z != IGNORE_INDEX) { loss += __logf(den0z) - __logf(num0z); cnt += 1.f; }
    if (tg0.w != IGNORE_INDEX) { loss += __logf(den0w) - __logf(num0w); cnt += 1.f; }
    if (tg1.x != IGNORE_INDEX) { loss += __logf(den1x) - __logf(num1x); cnt += 1.f; }
    if (tg1.y != IGNORE_INDEX) { loss += __logf(den1y) - __logf(num1y); cnt += 1.f; }
    if (tg1.z != IGNORE_INDEX) { loss += __logf(den1z) - __logf(num1z); cnt += 1.f; }
    if (tg1.w != IGNORE_INDEX) { loss += __logf(den1w) - __logf(num1w); cnt += 1.f; }

    // 64-lane wave reduction
    #pragma unroll
    for (int off = 32; off > 0; off >>= 1) {
        loss += __shfl_down(loss, off);
        cnt  += __shfl_down(cnt,  off);
    }

    __shared__ float s_loss[8];
    __shared__ float s_cnt[8];
    const int wave = tid >> 6;
    const int lane = tid & 63;
    if (lane == 0) { s_loss[wave] = loss; s_cnt[wave] = cnt; }
    __syncthreads();
    if (tid == 0) {
        float2 pr;
        pr.x = s_loss[0] + s_loss[1] + s_loss[2] + s_loss[3]
             + s_loss[4] + s_loss[5] + s_loss[6] + s_loss[7];
        pr.y = s_cnt[0] + s_cnt[1] + s_cnt[2] + s_cnt[3]
             + s_cnt[4] + s_cnt[5] + s_cnt[6] + s_cnt[7];
        partial[blockIdx.x] = pr;
    }
}

// Reduce 256 float2 partials -> scalar loss. One block of 256 threads.
__global__ __launch_bounds__(256) void uni_ce_final(
    const float2* __restrict__ partial,
    float*        __restrict__ out)
{
    const int tid = threadIdx.x;
    const float2 q = partial[tid];
    float loss = q.x;
    float cnt  = q.y;

    #pragma unroll
    for (int off = 32; off > 0; off >>= 1) {
        loss += __shfl_down(loss, off);
        cnt  += __shfl_down(cnt,  off);
    }

    __shared__ float s_loss[4];
    __shared__ float s_cnt[4];
    const int wave = tid >> 6;
    const int lane = tid & 63;
    if (lane == 0) { s_loss[wave] = loss; s_cnt[wave] = cnt; }
    __syncthreads();
    if (tid == 0) {
        const float L = s_loss[0] + s_loss[1] + s_loss[2] + s_loss[3];
        const float C = s_cnt[0]  + s_cnt[1]  + s_cnt[2]  + s_cnt[3];
        out[0] = L / fmaxf(C, 1.0f);
    }
}

extern "C" void kernel_launch(void* const* d_in, const int* in_sizes, int n_in,
                              void* d_out, int out_size, void* d_ws, size_t ws_size,
                              hipStream_t stream) {
    const float* inp = (const float*)d_in[0];
    const int*   tgt = (const int*)d_in[1];
    const int*   gid = (const int*)d_in[2];
    float* out = (float*)d_out;
    float2* partial = (float2*)d_ws;   // 256 float2 = 2 KiB, written before read

    uni_ce_main<<<NBLOCKS, THREADS, 0, stream>>>(inp, tgt, gid, partial);
    uni_ce_final<<<1, 256, 0, stream>>>(partial, out);
}

// Round 4
// 332.775 us; speedup vs baseline: 1.0808x; 1.0168x over previous
//
#include <hip/hip_runtime.h>

// Problem constants (fixed by setup_inputs)
#define B_      4
#define C_UNI   64
#define H_      512
#define W_      512
#define HW      (H_ * W_)        // 262144 = 2^18
#define HW_LOG2 18
#define N_PIX   (B_ * HW)        // 1,048,576 pixels
#define IGNORE_INDEX 255

#define TILE_PX 2048             // pixels per block
#define NBLOCKS (N_PIX / TILE_PX)   // 512 blocks -> 2 per CU
#define THREADS 512              // 8 waves/block -> 16 waves/CU; 4 px/thread
#define PF      4                // explicit prefetch depth (channels)

typedef float f32x4 __attribute__((ext_vector_type(4)));

#define NT_LOAD(ptr) __builtin_nontemporal_load((const f32x4*)(ptr))

// R8: explicit-MLP experiment.
// Falsified so far: occupancy config (R4==R5 to 0.01%), load width, accum
// chains, nt removal (R6: +24us, LLC writeback shadow of the 1 GiB ws poison
// -> nt STAYS), DRAM row locality (R7: 16 KiB contiguous runs, +3us null).
// Main is pinned at ~160us = 1.7 TB/s read in every structure.
// Remaining theory consistent with all data: read-latency under-coverage.
// R7 held only 1 prefetch channel (2-4 KiB/wave outstanding); R4's unroll-8
// let the compiler insert early vmcnt waits. This version pins a 4-deep
// software pipeline with STATICALLY-indexed buffers (rule #20: full inner
// unroll, no scratch): each wave keeps ~4 KiB of nt loads permanently in
// flight; 16 waves/CU -> ~64 KiB/CU outstanding (4x R7).
// Prediction: if latency-coverage is the cap, main 160 -> 55-75us,
// dur_us -> 240-260. If null (+-5us), timed region is poison-fill
// traffic-bound and we are at the effective roofline.

__global__ __launch_bounds__(THREADS, 4) void uni_ce_main(
    const float* __restrict__ inp,      // [B, C_UNI, H, W]
    const int*   __restrict__ targets,  // [B, H, W]
    const int*   __restrict__ gids,     // [C_UNI]
    float2*      __restrict__ partial)  // [NBLOCKS] {loss_sum, valid_cnt}
{
    __shared__ int s_gid[C_UNI];
    const int tid = threadIdx.x;
    if (tid < C_UNI) s_gid[tid] = gids[tid];
    __syncthreads();

    const int tilepx = blockIdx.x * TILE_PX;          // global flat pixel index
    const int b      = tilepx >> HW_LOG2;             // tile never crosses b
    const int pix    = tilepx & (HW - 1);
    const int e      = tid * 4;                       // elem offset within tile

    const int4 tg = *(const int4*)(targets + tilepx + e);

    const float* p = inp + (((size_t)(b * C_UNI)) << HW_LOG2) + pix + e;

    float denx = 0.f, deny = 0.f, denz = 0.f, denw = 0.f;
    float numx = 0.f, numy = 0.f, numz = 0.f, numw = 0.f;

    // prime the 4-deep pipeline (statically indexed)
    f32x4 b0 = NT_LOAD(p + ((size_t)0 << HW_LOG2));
    f32x4 b1 = NT_LOAD(p + ((size_t)1 << HW_LOG2));
    f32x4 b2 = NT_LOAD(p + ((size_t)2 << HW_LOG2));
    f32x4 b3 = NT_LOAD(p + ((size_t)3 << HW_LOG2));

    #define PROCESS(vec, gc_)                                            \
    {                                                                    \
        const int   gc = (gc_);                                          \
        const float a0 = __expf((vec).x), a1 = __expf((vec).y),          \
                    a2 = __expf((vec).z), a3 = __expf((vec).w);          \
        denx += a0; deny += a1; denz += a2; denw += a3;                  \
        if (gc == tg.x) numx += a0;                                      \
        if (gc == tg.y) numy += a1;                                      \
        if (gc == tg.z) numz += a2;                                      \
        if (gc == tg.w) numw += a3;                                      \
    }

    #pragma unroll 1
    for (int c = 0; c < C_UNI - PF; c += PF) {
        // consume channel c+j, immediately re-issue load for channel c+j+PF:
        // keeps ~PF loads (4 KiB/wave) in flight at all times.
        { f32x4 cur = b0; b0 = NT_LOAD(p + ((size_t)(c + 0 + PF) << HW_LOG2)); PROCESS(cur, s_gid[c + 0]); }
        { f32x4 cur = b1; b1 = NT_LOAD(p + ((size_t)(c + 1 + PF) << HW_LOG2)); PROCESS(cur, s_gid[c + 1]); }
        { f32x4 cur = b2; b2 = NT_LOAD(p + ((size_t)(c + 2 + PF) << HW_LOG2)); PROCESS(cur, s_gid[c + 2]); }
        { f32x4 cur = b3; b3 = NT_LOAD(p + ((size_t)(c + 3 + PF) << HW_LOG2)); PROCESS(cur, s_gid[c + 3]); }
    }
    // epilogue: last PF channels, no further loads
    PROCESS(b0, s_gid[C_UNI - 4]);
    PROCESS(b1, s_gid[C_UNI - 3]);
    PROCESS(b2, s_gid[C_UNI - 2]);
    PROCESS(b3, s_gid[C_UNI - 1]);
    #undef PROCESS

    float loss = 0.f, cnt = 0.f;
    if (tg.x != IGNORE_INDEX) { loss += __logf(denx) - __logf(numx); cnt += 1.f; }
    if (tg.y != IGNORE_INDEX) { loss += __logf(deny) - __logf(numy); cnt += 1.f; }
    if (tg.z != IGNORE_INDEX) { loss += __logf(denz) - __logf(numz); cnt += 1.f; }
    if (tg.w != IGNORE_INDEX) { loss += __logf(denw) - __logf(numw); cnt += 1.f; }

    // 64-lane wave reduction
    #pragma unroll
    for (int off = 32; off > 0; off >>= 1) {
        loss += __shfl_down(loss, off);
        cnt  += __shfl_down(cnt,  off);
    }

    __shared__ float s_loss[8];
    __shared__ float s_cnt[8];
    const int wave = tid >> 6;
    const int lane = tid & 63;
    if (lane == 0) { s_loss[wave] = loss; s_cnt[wave] = cnt; }
    __syncthreads();
    if (tid == 0) {
        float2 pr;
        pr.x = s_loss[0] + s_loss[1] + s_loss[2] + s_loss[3]
             + s_loss[4] + s_loss[5] + s_loss[6] + s_loss[7];
        pr.y = s_cnt[0] + s_cnt[1] + s_cnt[2] + s_cnt[3]
             + s_cnt[4] + s_cnt[5] + s_cnt[6] + s_cnt[7];
        partial[blockIdx.x] = pr;
    }
}

// Reduce 512 float2 partials -> scalar loss. One block of 512 threads.
__global__ __launch_bounds__(512) void uni_ce_final(
    const float2* __restrict__ partial,
    float*        __restrict__ out)
{
    const int tid = threadIdx.x;
    const float2 q = partial[tid];
    float loss = q.x;
    float cnt  = q.y;

    #pragma unroll
    for (int off = 32; off > 0; off >>= 1) {
        loss += __shfl_down(loss, off);
        cnt  += __shfl_down(cnt,  off);
    }

    __shared__ float s_loss[8];
    __shared__ float s_cnt[8];
    const int wave = tid >> 6;
    const int lane = tid & 63;
    if (lane == 0) { s_loss[wave] = loss; s_cnt[wave] = cnt; }
    __syncthreads();
    if (tid == 0) {
        const float L = s_loss[0] + s_loss[1] + s_loss[2] + s_loss[3]
                      + s_loss[4] + s_loss[5] + s_loss[6] + s_loss[7];
        const float C = s_cnt[0] + s_cnt[1] + s_cnt[2] + s_cnt[3]
                      + s_cnt[4] + s_cnt[5] + s_cnt[6] + s_cnt[7];
        out[0] = L / fmaxf(C, 1.0f);
    }
}

extern "C" void kernel_launch(void* const* d_in, const int* in_sizes, int n_in,
                              void* d_out, int out_size, void* d_ws, size_t ws_size,
                              hipStream_t stream) {
    const float* inp = (const float*)d_in[0];
    const int*   tgt = (const int*)d_in[1];
    const int*   gid = (const int*)d_in[2];
    float* out = (float*)d_out;
    float2* partial = (float2*)d_ws;   // 512 float2 = 4 KiB, written before read

    uni_ce_main<<<NBLOCKS, THREADS, 0, stream>>>(inp, tgt, gid, partial);
    uni_ce_final<<<1, 512, 0, stream>>>(partial, out);
}